// Round 6
// baseline (132.069 us; speedup 1.0000x reference)
//
#include <hip/hip_runtime.h>
#include <math.h>

#define C_CH   256
#define HW     4096              // H*W = 64*64
#define B_N    32
#define N_PER_CH (B_N * HW)      // 131072 elements reduced per channel
#define N_TOT  ((size_t)B_N * C_CH * HW) // 33554432 elements per plane
#define EPS_BN 1e-5f

#define JR 10                    // slabs retained in registers (per thread: 2*JR float4)
#define JL 4                     // slabs retained in LDS (2*JL*16 KiB = 128 KiB)

typedef float f32x4 __attribute__((ext_vector_type(4)));

// ---------------------------------------------------------------------------
// One block per channel (grid=256 -> 1 block/CU, forced by 128 KiB LDS).
// Phase 1: stream the channel's 32 slabs (1 MiB), accumulating 5 sums.
//          Slabs 0..JR-1 are kept in VGPRs, slabs JR..JR+JL-1 in LDS,
//          the rest are read-and-discarded (they get re-read in phase 2).
// Phase 2: derive per-channel coefficients, then write output: retained
//          slabs come from regs/LDS (no HBM), the remaining 18 slabs are
//          re-read with nt loads.  All stores non-temporal.
// Cache-steering was measured null 3x (MALL is memory-side; the write
// stream evicts the inputs regardless of nt hints) -> retention is physical.
// Output layout [2, B, C, H, W]: real plane first, imag plane at +N_TOT.
// ---------------------------------------------------------------------------
__global__ __launch_bounds__(1024, 4) void cbn_fused(
    const float* __restrict__ xr, const float* __restrict__ xi,
    const float* __restrict__ weight,   // [2,2,C]
    const float* __restrict__ bias,     // [2,C]
    float* __restrict__ out)
{
    const int c = blockIdx.x;
    const int t = threadIdx.x;
    const f32x4* r4 = reinterpret_cast<const f32x4*>(xr);
    const f32x4* i4 = reinterpret_cast<const f32x4*>(xi);

    __shared__ f32x4 lr[JL][1024];
    __shared__ f32x4 li[JL][1024];
    __shared__ float red[5][16];
    __shared__ float scoef[6];

    float sr = 0.f, si = 0.f, srr = 0.f, sii = 0.f, sri = 0.f;
    f32x4 ra[JR], ia[JR];

    // ---- phase 1a: register-retained slabs (nt loads: never re-read) ------
#pragma unroll
    for (int j = 0; j < JR; ++j) {
        const size_t idx = ((size_t)(j * C_CH + c) << 10) + t;
        const f32x4 a = __builtin_nontemporal_load(&r4[idx]);
        const f32x4 b = __builtin_nontemporal_load(&i4[idx]);
        ra[j] = a; ia[j] = b;
        sr  += a.x + a.y + a.z + a.w;
        si  += b.x + b.y + b.z + b.w;
        srr += a.x * a.x + a.y * a.y + a.z * a.z + a.w * a.w;
        sii += b.x * b.x + b.y * b.y + b.z * b.z + b.w * b.w;
        sri += a.x * b.x + a.y * b.y + a.z * b.z + a.w * b.w;
    }
    // ---- phase 1b: LDS-retained slabs --------------------------------------
#pragma unroll
    for (int j = 0; j < JL; ++j) {
        const size_t idx = ((size_t)((JR + j) * C_CH + c) << 10) + t;
        const f32x4 a = __builtin_nontemporal_load(&r4[idx]);
        const f32x4 b = __builtin_nontemporal_load(&i4[idx]);
        lr[j][t] = a; li[j][t] = b;
        sr  += a.x + a.y + a.z + a.w;
        si  += b.x + b.y + b.z + b.w;
        srr += a.x * a.x + a.y * a.y + a.z * a.z + a.w * a.w;
        sii += b.x * b.x + b.y * b.y + b.z * b.z + b.w * b.w;
        sri += a.x * b.x + a.y * b.y + a.z * b.z + a.w * b.w;
    }
    // ---- phase 1c: streamed slabs (temporal: will be re-read) --------------
#pragma unroll 2
    for (int j = JR + JL; j < B_N; ++j) {
        const size_t idx = ((size_t)(j * C_CH + c) << 10) + t;
        const f32x4 a = r4[idx];
        const f32x4 b = i4[idx];
        sr  += a.x + a.y + a.z + a.w;
        si  += b.x + b.y + b.z + b.w;
        srr += a.x * a.x + a.y * a.y + a.z * a.z + a.w * a.w;
        sii += b.x * b.x + b.y * b.y + b.z * b.z + b.w * b.w;
        sri += a.x * b.x + a.y * b.y + a.z * b.z + a.w * b.w;
    }

    // ---- reduction across 1024 threads ------------------------------------
#pragma unroll
    for (int off = 32; off > 0; off >>= 1) {
        sr  += __shfl_down(sr,  off);
        si  += __shfl_down(si,  off);
        srr += __shfl_down(srr, off);
        sii += __shfl_down(sii, off);
        sri += __shfl_down(sri, off);
    }
    const int wave = t >> 6;
    if ((t & 63) == 0) {
        red[0][wave] = sr;  red[1][wave] = si;
        red[2][wave] = srr; red[3][wave] = sii; red[4][wave] = sri;
    }
    __syncthreads();

    if (t < 64) {
        float v0 = 0.f, v1 = 0.f, v2 = 0.f, v3 = 0.f, v4 = 0.f;
        if (t < 16) {
            v0 = red[0][t]; v1 = red[1][t]; v2 = red[2][t];
            v3 = red[3][t]; v4 = red[4][t];
        }
#pragma unroll
        for (int off = 8; off > 0; off >>= 1) {
            v0 += __shfl_down(v0, off);
            v1 += __shfl_down(v1, off);
            v2 += __shfl_down(v2, off);
            v3 += __shfl_down(v3, off);
            v4 += __shfl_down(v4, off);
        }
        if (t == 0) {
            const float invN = 1.0f / (float)N_PER_CH;
            const float mur = v0 * invN;
            const float mui = v1 * invN;
            const float Vrr = v2 * invN - mur * mur + EPS_BN;
            const float Vii = v3 * invN - mui * mui + EPS_BN;
            const float Vri = v4 * invN - mur * mui;

            const float s      = sqrtf(Vrr * Vii - Vri * Vri);
            const float tt     = sqrtf(Vrr + Vii + 2.0f * s);
            const float inv_st = 1.0f / (s * tt);
            const float Rrr = (Vii + s) * inv_st;
            const float Rii = (Vrr + s) * inv_st;
            const float Rri = -Vri * inv_st;

            const float w00 = weight[0 * C_CH + c];
            const float w01 = weight[1 * C_CH + c];
            const float w10 = weight[2 * C_CH + c];
            const float w11 = weight[3 * C_CH + c];
            const float b0  = bias[c];
            const float b1  = bias[C_CH + c];

            const float Ar = w00 * Rrr + w01 * Rri;
            const float Br = w00 * Rri + w01 * Rii;
            const float Ai = w10 * Rrr + w11 * Rri;
            const float Bi = w10 * Rri + w11 * Rii;

            scoef[0] = Ar;
            scoef[1] = Br;
            scoef[2] = b0 - Ar * mur - Br * mui;
            scoef[3] = Ai;
            scoef[4] = Bi;
            scoef[5] = b1 - Ai * mur - Bi * mui;
        }
    }
    __syncthreads();

    const float Ar = scoef[0], Br = scoef[1], Cr = scoef[2];
    const float Ai = scoef[3], Bi = scoef[4], Ci = scoef[5];

    f32x4* o4 = reinterpret_cast<f32x4*>(out);
    const size_t n4 = N_TOT / 4;

    // ---- phase 2a: register-resident slabs ---------------------------------
#pragma unroll
    for (int j = 0; j < JR; ++j) {
        const size_t idx = ((size_t)(j * C_CH + c) << 10) + t;
        const f32x4 a = ra[j];
        const f32x4 b = ia[j];
        f32x4 u, v;
        u.x = Ar * a.x + Br * b.x + Cr;
        u.y = Ar * a.y + Br * b.y + Cr;
        u.z = Ar * a.z + Br * b.z + Cr;
        u.w = Ar * a.w + Br * b.w + Cr;
        v.x = Ai * a.x + Bi * b.x + Ci;
        v.y = Ai * a.y + Bi * b.y + Ci;
        v.z = Ai * a.z + Bi * b.z + Ci;
        v.w = Ai * a.w + Bi * b.w + Ci;
        __builtin_nontemporal_store(u, &o4[idx]);
        __builtin_nontemporal_store(v, &o4[n4 + idx]);
    }
    // ---- phase 2b: LDS-resident slabs --------------------------------------
#pragma unroll
    for (int j = 0; j < JL; ++j) {
        const size_t idx = ((size_t)((JR + j) * C_CH + c) << 10) + t;
        const f32x4 a = lr[j][t];
        const f32x4 b = li[j][t];
        f32x4 u, v;
        u.x = Ar * a.x + Br * b.x + Cr;
        u.y = Ar * a.y + Br * b.y + Cr;
        u.z = Ar * a.z + Br * b.z + Cr;
        u.w = Ar * a.w + Br * b.w + Cr;
        v.x = Ai * a.x + Bi * b.x + Ci;
        v.y = Ai * a.y + Bi * b.y + Ci;
        v.z = Ai * a.z + Bi * b.z + Ci;
        v.w = Ai * a.w + Bi * b.w + Ci;
        __builtin_nontemporal_store(u, &o4[idx]);
        __builtin_nontemporal_store(v, &o4[n4 + idx]);
    }
    // ---- phase 2c: streamed slabs (HBM re-read, nt) ------------------------
#pragma unroll 2
    for (int j = JR + JL; j < B_N; ++j) {
        const size_t idx = ((size_t)(j * C_CH + c) << 10) + t;
        const f32x4 a = __builtin_nontemporal_load(&r4[idx]);
        const f32x4 b = __builtin_nontemporal_load(&i4[idx]);
        f32x4 u, v;
        u.x = Ar * a.x + Br * b.x + Cr;
        u.y = Ar * a.y + Br * b.y + Cr;
        u.z = Ar * a.z + Br * b.z + Cr;
        u.w = Ar * a.w + Br * b.w + Cr;
        v.x = Ai * a.x + Bi * b.x + Ci;
        v.y = Ai * a.y + Bi * b.y + Ci;
        v.z = Ai * a.z + Bi * b.z + Ci;
        v.w = Ai * a.w + Bi * b.w + Ci;
        __builtin_nontemporal_store(u, &o4[idx]);
        __builtin_nontemporal_store(v, &o4[n4 + idx]);
    }
}

extern "C" void kernel_launch(void* const* d_in, const int* in_sizes, int n_in,
                              void* d_out, int out_size, void* d_ws, size_t ws_size,
                              hipStream_t stream) {
    const float* xr     = (const float*)d_in[0];
    const float* xi     = (const float*)d_in[1];
    const float* weight = (const float*)d_in[2];
    const float* bias   = (const float*)d_in[3];
    float* out = (float*)d_out;

    cbn_fused<<<C_CH, 1024, 0, stream>>>(xr, xi, weight, bias, out);
}

// Round 7
// 130.164 us; speedup vs baseline: 1.0146x; 1.0146x over previous
//
#include <hip/hip_runtime.h>
#include <math.h>

#define C_CH   256
#define HW     4096              // H*W = 64*64
#define B_N    32
#define N_PER_CH (B_N * HW)      // 131072 elements reduced per channel
#define N_TOT  ((size_t)B_N * C_CH * HW) // 33554432 elements per plane
#define EPS_BN 1e-5f

#define GCH    64                // channels per epoch group (4 epochs)
#define QS     8                 // slabs per quarter (4 quarters x 8 = 32 batches)
#define NT     512               // threads per block

typedef float f32x4 __attribute__((ext_vector_type(4)));

// ---------------------------------------------------------------------------
// Epoch-sliced complex BatchNorm.
// Launch sequence: P(0), [A(0)+P(1)], [A(1)+P(2)], [A(2)+P(3)], A(3).
// Each kernel: 256 blocks = 64 channels x 4 quarters (8 slabs each).
//   APPLY part (apply_g >= 0): fold the 4 quarter-partials of the channel
//     into 6 coefficients, then out = A*xr + B*xi + C with nt loads (data
//     was streamed by the PREVIOUS kernel's stats part -> chip-level reuse
//     distance ~134-200 MB < 256 MB MALL -> L3 hit) and nt stores.
//   STATS part (stats_g >= 0): stream the quarter's 8 slabs with TEMPORAL
//     loads (allocate in MALL for the next kernel's apply), accumulate 5
//     sums, write part[ch*20 + q*5 + k].
// Rationale: R5 proved per-block reuse is irrelevant -- all blocks stream
// concurrently, so reuse distance is chip-wide.  Epochs shrink it 4x.
// Output layout [2, B, C, H, W]: real plane first, imag plane at +N_TOT.
// ---------------------------------------------------------------------------
__global__ __launch_bounds__(NT) void cbn_epoch(
    const float* __restrict__ xr, const float* __restrict__ xi,
    const float* __restrict__ weight,   // [2,2,C]
    const float* __restrict__ bias,     // [2,C]
    float* __restrict__ out,
    float* __restrict__ part,
    const int apply_g, const int stats_g)
{
    const int blk = blockIdx.x;
    const int t   = threadIdx.x;
    const f32x4* r4 = reinterpret_cast<const f32x4*>(xr);
    const f32x4* i4 = reinterpret_cast<const f32x4*>(xi);

    __shared__ float sp[20];
    __shared__ float scoef[6];
    __shared__ float red[5][8];

    // ======================= APPLY part (group apply_g) =====================
    if (apply_g >= 0) {
        const int ch = apply_g * GCH + (blk >> 2);
        const int q  = blk & 3;

        if (t < 20) sp[t] = part[ch * 20 + t];
        __syncthreads();
        if (t == 0) {
            const float v0 = sp[0] + sp[5]  + sp[10] + sp[15];
            const float v1 = sp[1] + sp[6]  + sp[11] + sp[16];
            const float v2 = sp[2] + sp[7]  + sp[12] + sp[17];
            const float v3 = sp[3] + sp[8]  + sp[13] + sp[18];
            const float v4 = sp[4] + sp[9]  + sp[14] + sp[19];

            const float invN = 1.0f / (float)N_PER_CH;
            const float mur = v0 * invN;
            const float mui = v1 * invN;
            const float Vrr = v2 * invN - mur * mur + EPS_BN;
            const float Vii = v3 * invN - mui * mui + EPS_BN;
            const float Vri = v4 * invN - mur * mui;

            const float s      = sqrtf(Vrr * Vii - Vri * Vri);
            const float tt     = sqrtf(Vrr + Vii + 2.0f * s);
            const float inv_st = 1.0f / (s * tt);
            const float Rrr = (Vii + s) * inv_st;
            const float Rii = (Vrr + s) * inv_st;
            const float Rri = -Vri * inv_st;

            const float w00 = weight[0 * C_CH + ch];
            const float w01 = weight[1 * C_CH + ch];
            const float w10 = weight[2 * C_CH + ch];
            const float w11 = weight[3 * C_CH + ch];
            const float b0  = bias[ch];
            const float b1  = bias[C_CH + ch];

            const float Ar = w00 * Rrr + w01 * Rri;
            const float Br = w00 * Rri + w01 * Rii;
            const float Ai = w10 * Rrr + w11 * Rri;
            const float Bi = w10 * Rri + w11 * Rii;

            scoef[0] = Ar;
            scoef[1] = Br;
            scoef[2] = b0 - Ar * mur - Br * mui;
            scoef[3] = Ai;
            scoef[4] = Bi;
            scoef[5] = b1 - Ai * mur - Bi * mui;
        }
        __syncthreads();

        const float Ar = scoef[0], Br = scoef[1], Cr = scoef[2];
        const float Ai = scoef[3], Bi = scoef[4], Ci = scoef[5];

        f32x4* o4 = reinterpret_cast<f32x4*>(out);
        const size_t n4 = N_TOT / 4;

#pragma unroll 2
        for (int j = q * QS; j < q * QS + QS; ++j) {
            const size_t base = ((size_t)(j * C_CH + ch) << 10);
#pragma unroll
            for (int k = 0; k < 2; ++k) {
                const size_t idx = base + (size_t)k * NT + t;
                const f32x4 a = __builtin_nontemporal_load(&r4[idx]);
                const f32x4 b = __builtin_nontemporal_load(&i4[idx]);
                f32x4 u, v;
                u.x = Ar * a.x + Br * b.x + Cr;
                u.y = Ar * a.y + Br * b.y + Cr;
                u.z = Ar * a.z + Br * b.z + Cr;
                u.w = Ar * a.w + Br * b.w + Cr;
                v.x = Ai * a.x + Bi * b.x + Ci;
                v.y = Ai * a.y + Bi * b.y + Ci;
                v.z = Ai * a.z + Bi * b.z + Ci;
                v.w = Ai * a.w + Bi * b.w + Ci;
                __builtin_nontemporal_store(u, &o4[idx]);
                __builtin_nontemporal_store(v, &o4[n4 + idx]);
            }
        }
    }

    // ======================= STATS part (group stats_g) =====================
    if (stats_g >= 0) {
        const int ch = stats_g * GCH + (blk >> 2);
        const int q  = blk & 3;

        float sr = 0.f, si = 0.f, srr = 0.f, sii = 0.f, sri = 0.f;
#pragma unroll 2
        for (int j = q * QS; j < q * QS + QS; ++j) {
            const size_t base = ((size_t)(j * C_CH + ch) << 10);
#pragma unroll
            for (int k = 0; k < 2; ++k) {
                const size_t idx = base + (size_t)k * NT + t;
                const f32x4 a = r4[idx];     // temporal: warm MALL for apply
                const f32x4 b = i4[idx];
                sr  += a.x + a.y + a.z + a.w;
                si  += b.x + b.y + b.z + b.w;
                srr += a.x * a.x + a.y * a.y + a.z * a.z + a.w * a.w;
                sii += b.x * b.x + b.y * b.y + b.z * b.z + b.w * b.w;
                sri += a.x * b.x + a.y * b.y + a.z * b.z + a.w * b.w;
            }
        }

#pragma unroll
        for (int off = 32; off > 0; off >>= 1) {
            sr  += __shfl_down(sr,  off);
            si  += __shfl_down(si,  off);
            srr += __shfl_down(srr, off);
            sii += __shfl_down(sii, off);
            sri += __shfl_down(sri, off);
        }
        const int wave = t >> 6;
        if ((t & 63) == 0) {
            red[0][wave] = sr;  red[1][wave] = si;
            red[2][wave] = srr; red[3][wave] = sii; red[4][wave] = sri;
        }
        __syncthreads();
        if (t == 0) {
#pragma unroll
            for (int k = 0; k < 5; ++k) {
                float acc = red[k][0];
#pragma unroll
                for (int w = 1; w < NT / 64; ++w) acc += red[k][w];
                part[ch * 20 + q * 5 + k] = acc;
            }
        }
    }
}

extern "C" void kernel_launch(void* const* d_in, const int* in_sizes, int n_in,
                              void* d_out, int out_size, void* d_ws, size_t ws_size,
                              hipStream_t stream) {
    const float* xr     = (const float*)d_in[0];
    const float* xi     = (const float*)d_in[1];
    const float* weight = (const float*)d_in[2];
    const float* bias   = (const float*)d_in[3];
    float* out  = (float*)d_out;
    float* part = (float*)d_ws;        // 256 channels * 20 floats = 20 KiB

    // P(0), A(0)+P(1), A(1)+P(2), A(2)+P(3), A(3)
    cbn_epoch<<<256, NT, 0, stream>>>(xr, xi, weight, bias, out, part, -1, 0);
    cbn_epoch<<<256, NT, 0, stream>>>(xr, xi, weight, bias, out, part,  0, 1);
    cbn_epoch<<<256, NT, 0, stream>>>(xr, xi, weight, bias, out, part,  1, 2);
    cbn_epoch<<<256, NT, 0, stream>>>(xr, xi, weight, bias, out, part,  2, 3);
    cbn_epoch<<<256, NT, 0, stream>>>(xr, xi, weight, bias, out, part,  3, -1);
}

// Round 8
// 125.452 us; speedup vs baseline: 1.0528x; 1.0376x over previous
//
#include <hip/hip_runtime.h>
#include <math.h>

#define C_CH   256
#define HW     4096              // H*W
#define B_N    32
#define N_PER_CH (B_N * HW)      // 131072
#define N_TOT  ((size_t)B_N * C_CH * HW) // 33554432 per plane
#define EPS_BN 1e-5f

#define HALF   16                // slabs per block (half a channel's batches)
#define RS     6                 // slabs retained in registers
#define LS     2                 // slabs retained in LDS
// streamed slabs = HALF - RS - LS = 8 (re-read from HBM in apply)

typedef float f32x4 __attribute__((ext_vector_type(4)));

// ---------------------------------------------------------------------------
// Register/LDS-retention complex BatchNorm (single kernel).
// 512 blocks x 256 thr = 2 blocks/CU.  Block (c,h) owns batches h*16..h*16+15
// of channel c.  Per slab per thread: 4 f32x4 per plane.
//   regs: slabs 0..RS-1   (RS*8 f32x4 = 192 VGPRs of data)
//   LDS : slabs RS..RS+LS-1 (LS*32 KiB = 64 KiB)
//   HBM : slabs RS+LS..15 (read twice)
// Stats halves are combined across the channel's 2 blocks via device-scope
// atomics + flag spin (all 512 blocks co-resident at 2/CU; 2-term float add
// is order-independent -> deterministic).
// Cache-steering was measured null 4x -> retention is physical, not hinted.
// Output layout [2,B,C,H,W]: real plane, then imag plane at +N_TOT.
// ---------------------------------------------------------------------------
__global__ __launch_bounds__(256) void cbn_ret(
    const float* __restrict__ xr, const float* __restrict__ xi,
    const float* __restrict__ weight,   // [2,2,C]
    const float* __restrict__ bias,     // [2,C]
    float* __restrict__ out,
    float* __restrict__ part,           // [512][5]
    int*   __restrict__ flag)           // [512]
{
    const int b  = blockIdx.x;
    const int c  = b >> 1;
    const int h  = b & 1;
    const int t  = threadIdx.x;
    const int j0 = h * HALF;

    const f32x4* r4 = reinterpret_cast<const f32x4*>(xr);
    const f32x4* i4 = reinterpret_cast<const f32x4*>(xi);

    __shared__ f32x4 lsr[LS][1024];
    __shared__ f32x4 lsi[LS][1024];
    __shared__ float red[5][4];
    __shared__ float scoef[6];

    float sr = 0.f, si = 0.f, srr = 0.f, sii = 0.f, sri = 0.f;
    f32x4 ra[RS][4], ia[RS][4];

#define ACC(a, bb)                                              \
    sr  += a.x + a.y + a.z + a.w;                               \
    si  += bb.x + bb.y + bb.z + bb.w;                           \
    srr += a.x*a.x + a.y*a.y + a.z*a.z + a.w*a.w;               \
    sii += bb.x*bb.x + bb.y*bb.y + bb.z*bb.z + bb.w*bb.w;       \
    sri += a.x*bb.x + a.y*bb.y + a.z*bb.z + a.w*bb.w;

    // ---- phase 1a: register-retained slabs ---------------------------------
#pragma unroll
    for (int j = 0; j < RS; ++j) {
        const size_t base = ((size_t)((j0 + j) * C_CH + c) << 10);
#pragma unroll
        for (int k = 0; k < 4; ++k) {
            const f32x4 a  = __builtin_nontemporal_load(&r4[base + k * 256 + t]);
            const f32x4 bb = __builtin_nontemporal_load(&i4[base + k * 256 + t]);
            ra[j][k] = a; ia[j][k] = bb;
            ACC(a, bb)
        }
    }
    // ---- phase 1b: LDS-retained slabs --------------------------------------
#pragma unroll
    for (int j = 0; j < LS; ++j) {
        const size_t base = ((size_t)((j0 + RS + j) * C_CH + c) << 10);
#pragma unroll
        for (int k = 0; k < 4; ++k) {
            const f32x4 a  = __builtin_nontemporal_load(&r4[base + k * 256 + t]);
            const f32x4 bb = __builtin_nontemporal_load(&i4[base + k * 256 + t]);
            lsr[j][k * 256 + t] = a; lsi[j][k * 256 + t] = bb;
            ACC(a, bb)
        }
    }
    // ---- phase 1c: streamed slabs ------------------------------------------
#pragma unroll 2
    for (int j = RS + LS; j < HALF; ++j) {
        const size_t base = ((size_t)((j0 + j) * C_CH + c) << 10);
#pragma unroll
        for (int k = 0; k < 4; ++k) {
            const f32x4 a  = r4[base + k * 256 + t];
            const f32x4 bb = i4[base + k * 256 + t];
            ACC(a, bb)
        }
    }
#undef ACC

    // ---- block reduction ----------------------------------------------------
#pragma unroll
    for (int off = 32; off > 0; off >>= 1) {
        sr  += __shfl_down(sr,  off);
        si  += __shfl_down(si,  off);
        srr += __shfl_down(srr, off);
        sii += __shfl_down(sii, off);
        sri += __shfl_down(sri, off);
    }
    const int wave = t >> 6;
    if ((t & 63) == 0) {
        red[0][wave] = sr;  red[1][wave] = si;
        red[2][wave] = srr; red[3][wave] = sii; red[4][wave] = sri;
    }
    __syncthreads();

    // ---- cross-block combine + coefficients (thread 0) ----------------------
    if (t == 0) {
        float own[5];
#pragma unroll
        for (int k = 0; k < 5; ++k)
            own[k] = red[k][0] + red[k][1] + red[k][2] + red[k][3];

#pragma unroll
        for (int k = 0; k < 5; ++k)
            __hip_atomic_store(&part[b * 5 + k], own[k],
                               __ATOMIC_RELAXED, __HIP_MEMORY_SCOPE_AGENT);
        __hip_atomic_store(&flag[b], 1,
                           __ATOMIC_RELEASE, __HIP_MEMORY_SCOPE_AGENT);

        const int ob = (c << 1) | (h ^ 1);
        while (__hip_atomic_load(&flag[ob],
                                 __ATOMIC_ACQUIRE, __HIP_MEMORY_SCOPE_AGENT) == 0) {
            __builtin_amdgcn_s_sleep(8);
        }
        float v[5];
#pragma unroll
        for (int k = 0; k < 5; ++k) {
            const float oth = __hip_atomic_load(&part[ob * 5 + k],
                                                __ATOMIC_RELAXED, __HIP_MEMORY_SCOPE_AGENT);
            v[k] = own[k] + oth;     // 2-term add: order-independent
        }

        const float invN = 1.0f / (float)N_PER_CH;
        const float mur = v[0] * invN;
        const float mui = v[1] * invN;
        const float Vrr = v[2] * invN - mur * mur + EPS_BN;
        const float Vii = v[3] * invN - mui * mui + EPS_BN;
        const float Vri = v[4] * invN - mur * mui;

        const float s      = sqrtf(Vrr * Vii - Vri * Vri);
        const float tt     = sqrtf(Vrr + Vii + 2.0f * s);
        const float inv_st = 1.0f / (s * tt);
        const float Rrr = (Vii + s) * inv_st;
        const float Rii = (Vrr + s) * inv_st;
        const float Rri = -Vri * inv_st;

        const float w00 = weight[0 * C_CH + c];
        const float w01 = weight[1 * C_CH + c];
        const float w10 = weight[2 * C_CH + c];
        const float w11 = weight[3 * C_CH + c];
        const float b0  = bias[c];
        const float b1  = bias[C_CH + c];

        const float Ar = w00 * Rrr + w01 * Rri;
        const float Br = w00 * Rri + w01 * Rii;
        const float Ai = w10 * Rrr + w11 * Rri;
        const float Bi = w10 * Rri + w11 * Rii;

        scoef[0] = Ar;
        scoef[1] = Br;
        scoef[2] = b0 - Ar * mur - Br * mui;
        scoef[3] = Ai;
        scoef[4] = Bi;
        scoef[5] = b1 - Ai * mur - Bi * mui;
    }
    __syncthreads();

    const float Ar = scoef[0], Br = scoef[1], Cr = scoef[2];
    const float Ai = scoef[3], Bi = scoef[4], Ci = scoef[5];

    f32x4* o4 = reinterpret_cast<f32x4*>(out);
    const size_t n4 = N_TOT / 4;

#define APPLY_STORE(a, bb, idx)                                 \
    {   f32x4 u, w_;                                            \
        u.x = Ar*a.x + Br*bb.x + Cr;  u.y = Ar*a.y + Br*bb.y + Cr; \
        u.z = Ar*a.z + Br*bb.z + Cr;  u.w = Ar*a.w + Br*bb.w + Cr; \
        w_.x = Ai*a.x + Bi*bb.x + Ci; w_.y = Ai*a.y + Bi*bb.y + Ci;\
        w_.z = Ai*a.z + Bi*bb.z + Ci; w_.w = Ai*a.w + Bi*bb.w + Ci;\
        __builtin_nontemporal_store(u,  &o4[idx]);              \
        __builtin_nontemporal_store(w_, &o4[n4 + idx]); }

    // ---- phase 2a: register-resident slabs ----------------------------------
#pragma unroll
    for (int j = 0; j < RS; ++j) {
        const size_t base = ((size_t)((j0 + j) * C_CH + c) << 10);
#pragma unroll
        for (int k = 0; k < 4; ++k) {
            const f32x4 a  = ra[j][k];
            const f32x4 bb = ia[j][k];
            APPLY_STORE(a, bb, base + k * 256 + t)
        }
    }
    // ---- phase 2b: LDS-resident slabs ----------------------------------------
#pragma unroll
    for (int j = 0; j < LS; ++j) {
        const size_t base = ((size_t)((j0 + RS + j) * C_CH + c) << 10);
#pragma unroll
        for (int k = 0; k < 4; ++k) {
            const f32x4 a  = lsr[j][k * 256 + t];
            const f32x4 bb = lsi[j][k * 256 + t];
            APPLY_STORE(a, bb, base + k * 256 + t)
        }
    }
    // ---- phase 2c: streamed slabs (HBM re-read) -------------------------------
#pragma unroll 2
    for (int j = RS + LS; j < HALF; ++j) {
        const size_t base = ((size_t)((j0 + j) * C_CH + c) << 10);
#pragma unroll
        for (int k = 0; k < 4; ++k) {
            const f32x4 a  = __builtin_nontemporal_load(&r4[base + k * 256 + t]);
            const f32x4 bb = __builtin_nontemporal_load(&i4[base + k * 256 + t]);
            APPLY_STORE(a, bb, base + k * 256 + t)
        }
    }
#undef APPLY_STORE
}

extern "C" void kernel_launch(void* const* d_in, const int* in_sizes, int n_in,
                              void* d_out, int out_size, void* d_ws, size_t ws_size,
                              hipStream_t stream) {
    const float* xr     = (const float*)d_in[0];
    const float* xi     = (const float*)d_in[1];
    const float* weight = (const float*)d_in[2];
    const float* bias   = (const float*)d_in[3];
    float* out = (float*)d_out;

    int*   flag = (int*)d_ws;                 // [512]
    float* part = (float*)((char*)d_ws + 2048); // [512][5]

    // flags must be zero at every call (ws is not re-poisoned between replays)
    hipMemsetAsync(d_ws, 0, 2048, stream);

    cbn_ret<<<512, 256, 0, stream>>>(xr, xi, weight, bias, out, part, flag);
}

// Round 9
// 114.981 us; speedup vs baseline: 1.1486x; 1.0911x over previous
//
#include <hip/hip_runtime.h>
#include <math.h>

#define C_CH   256
#define HW     4096              // H*W
#define B_N    32
#define N_PER_CH (B_N * HW)      // 131072
#define N_TOT  ((size_t)B_N * C_CH * HW) // 33554432 per plane
#define EPS_BN 1e-5f

#define RS 6                     // slabs retained in registers (48 VGPRs data)
#define LS 4                     // slabs retained in LDS (128 KiB)
#define ST (B_N - RS - LS)       // 22 slabs streamed (re-read, L3-served)

typedef float f32x4 __attribute__((ext_vector_type(4)));

// ---------------------------------------------------------------------------
// Whole-channel retention kernel: 256 blocks x 1024 threads (1 block/CU,
// 16 waves/CU).  Block = channel; slab = one (batch, channel) 16 KiB plane
// pair; 1024 threads -> exactly one f32x4 per plane per thread per slab.
//   regs: slabs 0..RS-1          (2*RS f32x4 = 48 VGPRs of data)
//   LDS : slabs RS..RS+LS-1      (128 KiB)
//   HBM : slabs RS+LS..31        (184 MB chip-wide < 256 MB L3 -> re-read hits;
//                                 R8 measured FETCH 181 MB with this pattern)
// No cross-block sync (R8's flag-spin convoy removed).  VGPR cap at 1024
// thr/block is 128; RS=6 chosen so peak pressure stays below it (R6/R8
// spilled at 80-192 data VGPRs).  nt stores throughout; streamed re-read
// happens FIRST in phase 2 (shortest chip-level reuse distance).
// Output layout [2,B,C,H,W]: real plane, imag plane at +N_TOT.
// ---------------------------------------------------------------------------
__global__ __launch_bounds__(1024) void cbn_ret2(
    const float* __restrict__ xr, const float* __restrict__ xi,
    const float* __restrict__ weight,   // [2,2,C]
    const float* __restrict__ bias,     // [2,C]
    float* __restrict__ out)
{
    const int c = blockIdx.x;
    const int t = threadIdx.x;

    const f32x4* r4 = reinterpret_cast<const f32x4*>(xr);
    const f32x4* i4 = reinterpret_cast<const f32x4*>(xi);

    __shared__ f32x4 lsr[LS][1024];
    __shared__ f32x4 lsi[LS][1024];
    __shared__ float red[5][16];
    __shared__ float scoef[6];

    float sr = 0.f, si = 0.f, srr = 0.f, sii = 0.f, sri = 0.f;
    f32x4 ra[RS], ia[RS];

#define ACC(a, bb)                                              \
    sr  += a.x + a.y + a.z + a.w;                               \
    si  += bb.x + bb.y + bb.z + bb.w;                           \
    srr += a.x*a.x + a.y*a.y + a.z*a.z + a.w*a.w;               \
    sii += bb.x*bb.x + bb.y*bb.y + bb.z*bb.z + bb.w*bb.w;       \
    sri += a.x*bb.x + a.y*bb.y + a.z*bb.z + a.w*bb.w;

    // ---- phase 1a: register-retained slabs (nt: never re-read) -------------
#pragma unroll
    for (int j = 0; j < RS; ++j) {
        const size_t idx = ((size_t)(j * C_CH + c) << 10) + t;
        const f32x4 a  = __builtin_nontemporal_load(&r4[idx]);
        const f32x4 bb = __builtin_nontemporal_load(&i4[idx]);
        ra[j] = a; ia[j] = bb;
        ACC(a, bb)
    }
    // ---- phase 1b: LDS-retained slabs (nt: never re-read) ------------------
#pragma unroll
    for (int j = 0; j < LS; ++j) {
        const size_t idx = ((size_t)((RS + j) * C_CH + c) << 10) + t;
        const f32x4 a  = __builtin_nontemporal_load(&r4[idx]);
        const f32x4 bb = __builtin_nontemporal_load(&i4[idx]);
        lsr[j][t] = a; lsi[j][t] = bb;
        ACC(a, bb)
    }
    // ---- phase 1c: streamed slabs (temporal: allocate in L3 for re-read) ---
#pragma unroll 2
    for (int j = RS + LS; j < B_N; ++j) {
        const size_t idx = ((size_t)(j * C_CH + c) << 10) + t;
        const f32x4 a  = r4[idx];
        const f32x4 bb = i4[idx];
        ACC(a, bb)
    }
#undef ACC

    // ---- block reduction (16 waves) ----------------------------------------
#pragma unroll
    for (int off = 32; off > 0; off >>= 1) {
        sr  += __shfl_down(sr,  off);
        si  += __shfl_down(si,  off);
        srr += __shfl_down(srr, off);
        sii += __shfl_down(sii, off);
        sri += __shfl_down(sri, off);
    }
    const int wave = t >> 6;
    if ((t & 63) == 0) {
        red[0][wave] = sr;  red[1][wave] = si;
        red[2][wave] = srr; red[3][wave] = sii; red[4][wave] = sri;
    }
    __syncthreads();

    if (t < 64) {
        float v0 = 0.f, v1 = 0.f, v2 = 0.f, v3 = 0.f, v4 = 0.f;
        if (t < 16) {
            v0 = red[0][t]; v1 = red[1][t]; v2 = red[2][t];
            v3 = red[3][t]; v4 = red[4][t];
        }
#pragma unroll
        for (int off = 8; off > 0; off >>= 1) {
            v0 += __shfl_down(v0, off);
            v1 += __shfl_down(v1, off);
            v2 += __shfl_down(v2, off);
            v3 += __shfl_down(v3, off);
            v4 += __shfl_down(v4, off);
        }
        if (t == 0) {
            const float invN = 1.0f / (float)N_PER_CH;
            const float mur = v0 * invN;
            const float mui = v1 * invN;
            const float Vrr = v2 * invN - mur * mur + EPS_BN;
            const float Vii = v3 * invN - mui * mui + EPS_BN;
            const float Vri = v4 * invN - mur * mui;

            const float s      = sqrtf(Vrr * Vii - Vri * Vri);
            const float tt     = sqrtf(Vrr + Vii + 2.0f * s);
            const float inv_st = 1.0f / (s * tt);
            const float Rrr = (Vii + s) * inv_st;
            const float Rii = (Vrr + s) * inv_st;
            const float Rri = -Vri * inv_st;

            const float w00 = weight[0 * C_CH + c];
            const float w01 = weight[1 * C_CH + c];
            const float w10 = weight[2 * C_CH + c];
            const float w11 = weight[3 * C_CH + c];
            const float b0  = bias[c];
            const float b1  = bias[C_CH + c];

            const float Ar = w00 * Rrr + w01 * Rri;
            const float Br = w00 * Rri + w01 * Rii;
            const float Ai = w10 * Rrr + w11 * Rri;
            const float Bi = w10 * Rri + w11 * Rii;

            scoef[0] = Ar;
            scoef[1] = Br;
            scoef[2] = b0 - Ar * mur - Br * mui;
            scoef[3] = Ai;
            scoef[4] = Bi;
            scoef[5] = b1 - Ai * mur - Bi * mui;
        }
    }
    __syncthreads();

    const float Ar = scoef[0], Br = scoef[1], Cr = scoef[2];
    const float Ai = scoef[3], Bi = scoef[4], Ci = scoef[5];

    f32x4* o4 = reinterpret_cast<f32x4*>(out);
    const size_t n4 = N_TOT / 4;

#define APPLY_STORE(a, bb, idx)                                    \
    {   f32x4 u, w_;                                               \
        u.x = Ar*a.x + Br*bb.x + Cr;  u.y = Ar*a.y + Br*bb.y + Cr; \
        u.z = Ar*a.z + Br*bb.z + Cr;  u.w = Ar*a.w + Br*bb.w + Cr; \
        w_.x = Ai*a.x + Bi*bb.x + Ci; w_.y = Ai*a.y + Bi*bb.y + Ci;\
        w_.z = Ai*a.z + Bi*bb.z + Ci; w_.w = Ai*a.w + Bi*bb.w + Ci;\
        __builtin_nontemporal_store(u,  &o4[idx]);                 \
        __builtin_nontemporal_store(w_, &o4[n4 + idx]); }

    // ---- phase 2a: streamed slabs FIRST (freshest in L3, nt re-read) -------
#pragma unroll 2
    for (int j = RS + LS; j < B_N; ++j) {
        const size_t idx = ((size_t)(j * C_CH + c) << 10) + t;
        const f32x4 a  = __builtin_nontemporal_load(&r4[idx]);
        const f32x4 bb = __builtin_nontemporal_load(&i4[idx]);
        APPLY_STORE(a, bb, idx)
    }
    // ---- phase 2b: LDS-resident slabs --------------------------------------
#pragma unroll
    for (int j = 0; j < LS; ++j) {
        const size_t idx = ((size_t)((RS + j) * C_CH + c) << 10) + t;
        const f32x4 a  = lsr[j][t];
        const f32x4 bb = lsi[j][t];
        APPLY_STORE(a, bb, idx)
    }
    // ---- phase 2c: register-resident slabs ---------------------------------
#pragma unroll
    for (int j = 0; j < RS; ++j) {
        const size_t idx = ((size_t)(j * C_CH + c) << 10) + t;
        const f32x4 a  = ra[j];
        const f32x4 bb = ia[j];
        APPLY_STORE(a, bb, idx)
    }
#undef APPLY_STORE
}

extern "C" void kernel_launch(void* const* d_in, const int* in_sizes, int n_in,
                              void* d_out, int out_size, void* d_ws, size_t ws_size,
                              hipStream_t stream) {
    const float* xr     = (const float*)d_in[0];
    const float* xi     = (const float*)d_in[1];
    const float* weight = (const float*)d_in[2];
    const float* bias   = (const float*)d_in[3];
    float* out = (float*)d_out;

    cbn_ret2<<<C_CH, 1024, 0, stream>>>(xr, xi, weight, bias, out);
}